// Round 4
// baseline (102.743 us; speedup 1.0000x reference)
//
#include <hip/hip_runtime.h>

// MRConv1d: B=4, N=10000, C=128, K=16, OUT=128
// out[b,n,o] = relu( sum_c2 feat[b,n,c2]*W[o,c2] + bias[o] )
// feat[b,n,2c]   = x[b,n,c]
// feat[b,n,2c+1] = max_k( x[b, e0[b,n,k], c] - x[b, e1[b,n,k], c] )
//
// R4: stage x as f16 (native v_pk_add_f16/v_pk_max_f16 -> ~4x VALU cut in the
// gather/max loop vs bf16-unpack-to-f32), GEMM via mfma_f32_16x16x32_f16.
// Per-batch f16 slice = 2.56 MB, fits the 4 MiB per-XCD L2 (XCD-pinned blocks).

#define Bn 4
#define Nn 10000
#define Cn 128
#define Kn 16
#define OUTn 128
#define Mn 16           // nodes per block
#define FPAD 8          // sfeat row pad (row = 264 halfs = 528 B)

typedef _Float16 half8v __attribute__((ext_vector_type(8)));
typedef float floatx4 __attribute__((ext_vector_type(4)));

// ---- fused prep: blocks [0,2500) convert x fp32->f16; blocks [2500,2516)
// pack W into f16 B-fragments for mfma_f32_16x16x32_f16.
// Wh[((tile*8 + step)*64 + lane)*8 + j] = (f16)W[o][c2]
//   with o = tile*16 + (lane&15), c2 = step*32 + (lane>>4)*8 + j.
__global__ __launch_bounds__(256) void prep(const float* __restrict__ x,
                                            const float* __restrict__ W,
                                            _Float16* __restrict__ xh,
                                            _Float16* __restrict__ Wh) {
    if (blockIdx.x < 2500) {
        int i = blockIdx.x * 256 + threadIdx.x;      // 0..639999, 8 floats each
        const float4* x4 = (const float4*)x;
        float4 a = x4[2 * i];
        float4 c = x4[2 * i + 1];
        union { _Float16 h[8]; uint4 q; } pk;
        pk.h[0] = (_Float16)a.x; pk.h[1] = (_Float16)a.y;
        pk.h[2] = (_Float16)a.z; pk.h[3] = (_Float16)a.w;
        pk.h[4] = (_Float16)c.x; pk.h[5] = (_Float16)c.y;
        pk.h[6] = (_Float16)c.z; pk.h[7] = (_Float16)c.w;
        *(uint4*)(xh + 8 * (size_t)i) = pk.q;
    } else {
        int tid = (blockIdx.x - 2500) * 256 + threadIdx.x;   // 0..4095
        int lane = tid & 63;
        int step = (tid >> 6) & 7;
        int tile = tid >> 9;
        int o = tile * 16 + (lane & 15);
        int quad = lane >> 4;
        union { _Float16 h[8]; uint4 q; } pk;
#pragma unroll
        for (int j = 0; j < 8; ++j) {
            int c2 = step * 32 + quad * 8 + j;
            pk.h[j] = (_Float16)W[o * (2 * Cn) + c2];
        }
        *(uint4*)(Wh + (size_t)tid * 8) = pk.q;
    }
}

__global__ __launch_bounds__(256, 4) void mrconv_kernel(
    const _Float16* __restrict__ xh, const int* __restrict__ edge,
    const _Float16* __restrict__ Wh, const float* __restrict__ bias,
    float* __restrict__ out)
{
    __shared__ _Float16 sfeat[Mn][2 * Cn + FPAD];  // f16 feature tile, interleaved
    __shared__ int sidx[2][Mn][Kn];

    // XCD-aware mapping: batch b pinned to XCD slots {b, b+4}; each XCD's L2
    // serves one 2.56 MB f16 batch slice (fits 4 MiB).
    int bi = blockIdx.x;
    int slot = bi & 7;
    int b = slot & 3;
    int nb = (bi >> 3) * 2 + (slot >> 2);
    if (nb >= Nn / Mn) return;
    const int n0 = nb * Mn;
    const int gbase = b * Nn + n0;

    const int t = threadIdx.x;
    const int wv = t >> 6;      // wave 0..3
    const int lane = t & 63;

    // stage edge indices for the block's 16 nodes: 2*16*16 = 512 ints
    for (int i = t; i < 2 * Mn * Kn; i += 256) {
        int s = i >> 8;
        int m = (i >> 4) & 15;
        int k = i & 15;
        sidx[s][m][k] = edge[s * (Bn * Nn * Kn) + (gbase + m) * Kn + k];
    }
    __syncthreads();

    const _Float16* xbb = xh + (size_t)b * Nn * Cn;

    // phase 1: gather + max-relative, all in packed f16.
    // Quarter-wave per row: 16 lanes x 16 B = 256 B row; wave covers 4 nodes.
    // k chunked by 8 -> 16 short8 loads (16 KB/wave) in flight per chunk.
    {
        const int q = lane >> 4;          // quarter 0..3
        const int l16 = lane & 15;
        const int m = wv * 4 + q;         // node 0..15
        const int ch = l16 * 8;           // 8 channels per lane
        const half8v xs = *(const half8v*)(xbb + (n0 + m) * Cn + ch);
        half8v r;
#pragma unroll
        for (int e = 0; e < 8; ++e) r[e] = (_Float16)(-65504.0f);
#pragma unroll
        for (int kc = 0; kc < 2; ++kc) {
            half8v vj[8], vi[8];
#pragma unroll
            for (int u = 0; u < 8; ++u) {
                const int jj = sidx[0][m][kc * 8 + u];
                const int ii = sidx[1][m][kc * 8 + u];
                vj[u] = *(const half8v*)(xbb + jj * Cn + ch);
                vi[u] = *(const half8v*)(xbb + ii * Cn + ch);
            }
#pragma unroll
            for (int u = 0; u < 8; ++u) {
                half8v d = vj[u] - vi[u];                    // v_pk_add_f16 (neg)
                r = __builtin_elementwise_max(r, d);         // v_pk_max_f16
            }
        }
        // interleaved f16 row: {x_c, rel_c} pairs; lane covers c in [ch, ch+8)
        union { _Float16 h[16]; uint4 q[2]; } pk;
#pragma unroll
        for (int e = 0; e < 8; ++e) {
            pk.h[2 * e] = xs[e];
            pk.h[2 * e + 1] = r[e];
        }
        *(uint4*)&sfeat[m][2 * ch] = pk.q[0];
        *(uint4*)&sfeat[m][2 * ch + 8] = pk.q[1];
    }
    __syncthreads();

    // phase 2: out_tile[16 nodes][128] = feat[16][256] @ Wt[256][128], MFMA f16.
    const int m16 = lane & 15;
    const int quad = lane >> 4;
    floatx4 acc0 = {0.f, 0.f, 0.f, 0.f};
    floatx4 acc1 = {0.f, 0.f, 0.f, 0.f};
    const half8v* wh8 = (const half8v*)Wh;
    const int tile0 = 2 * wv, tile1 = 2 * wv + 1;
#pragma unroll
    for (int step = 0; step < 8; ++step) {
        // A frag: A[m=lane&15][k = quad*8 + j], k-base = step*32
        half8v a = *(const half8v*)&sfeat[m16][step * 32 + quad * 8];
        half8v b0 = wh8[(tile0 * 8 + step) * 64 + lane];
        half8v b1 = wh8[(tile1 * 8 + step) * 64 + lane];
        acc0 = __builtin_amdgcn_mfma_f32_16x16x32_f16(a, b0, acc0, 0, 0, 0);
        acc1 = __builtin_amdgcn_mfma_f32_16x16x32_f16(a, b1, acc1, 0, 0, 0);
    }
    // C/D layout: col = lane&15, row = quad*4 + reg
    const int o0 = tile0 * 16 + m16;
    const int o1 = tile1 * 16 + m16;
    const float bb0 = bias[o0], bb1 = bias[o1];
#pragma unroll
    for (int r = 0; r < 4; ++r) {
        int g = gbase + quad * 4 + r;
        out[g * OUTn + o0] = fmaxf(acc0[r] + bb0, 0.f);
        out[g * OUTn + o1] = fmaxf(acc1[r] + bb1, 0.f);
    }
}

extern "C" void kernel_launch(void* const* d_in, const int* in_sizes, int n_in,
                              void* d_out, int out_size, void* d_ws, size_t ws_size,
                              hipStream_t stream) {
    const float* x = (const float*)d_in[0];
    const int* edge = (const int*)d_in[1];
    const float* W = (const float*)d_in[2];
    const float* bias = (const float*)d_in[3];
    float* out = (float*)d_out;

    _Float16* Wh = (_Float16*)d_ws;                        // 64 KB
    _Float16* xh = (_Float16*)((char*)d_ws + 65536);       // 10.24 MB

    prep<<<2516, 256, 0, stream>>>(x, W, xh, Wh);
    mrconv_kernel<<<2560, 256, 0, stream>>>(xh, edge, Wh, bias, out);
}